// Round 10
// baseline (72.073 us; speedup 1.0000x reference)
//
#include <hip/hip_runtime.h>

// 3D trilinear warp (grid_sample, align_corners=True equivalent, zeros padding)
// src:  [B=2, C=1, D=160, H=192, W=224] f32
// flow: [B=2, 3,   D,     H,     W    ] f32  (d,h,w voxel displacements)
// out:  [B=2, C=1, D,     H,     W    ] f32
//
// LDS-staged gathers. Brick = 16x16x16 (4096 voxels, 1024 threads,
// 4 voxels/thread), halo 4 -> region 24x24x24 @ stride 25 = 57.6 KB LDS,
// 2 blocks/CU = 32 waves = 100% occupancy; staging redundancy 3.52
// floats/voxel (was 4.69). Bank conflicts are pure flow-noise (systematic
// lane->bank pattern is a free 2-way); structural, not fixable by layout.

#define DD 160
#define HH 192
#define WW 224
constexpr int DHW = DD * HH * WW;          // 6,881,280
constexpr int BLOCK = 1024;
// Brick: 16 x 16 x 16.
constexpr int DT = DD / 16;                // 10
constexpr int HT = HH / 16;                // 12
constexpr int WT = WW / 16;                // 14
constexpr int BRICKS_PER_B = DT * HT * WT; // 1680
constexpr int NWG = 2 * BRICKS_PER_B;      // 3360, divisible by 8
constexpr int NXCD = 8;
constexpr int CHUNK = NWG / NXCD;          // 420

// Staged region: halo 4 each side -> 24 x 24 x 24, w padded to 25.
constexpr int RD = 24, RH = 24, RWE = 24, RWP = 25;
constexpr int TILE_N = RD * RH * RWP;      // 14400 floats = 57.6 KB
constexpr int SROWS = RD * RH;             // 576 staging rows
constexpr int SCHUNKS = SROWS * 6;         // 3456 float4 chunks

typedef float vfloat4 __attribute__((ext_vector_type(4)));

// Global fallback tap (rare): branchless, clamped, validity in weights.
__device__ __forceinline__ float trilerp_global(const float* __restrict__ sbase,
                                                float cd, float ch, float cw) {
    float d0f = floorf(cd), h0f = floorf(ch), w0f = floorf(cw);
    float fd = cd - d0f, fh = ch - h0f, fw = cw - w0f;
    int d0 = (int)d0f, h0 = (int)h0f, w0 = (int)w0f;
    int d1 = d0 + 1, h1 = h0 + 1, w1 = w0 + 1;

    float wd0 = (1.0f - fd) * ((unsigned)d0 < (unsigned)DD ? 1.0f : 0.0f);
    float wd1 = fd          * ((unsigned)d1 < (unsigned)DD ? 1.0f : 0.0f);
    float wh0 = (1.0f - fh) * ((unsigned)h0 < (unsigned)HH ? 1.0f : 0.0f);
    float wh1 = fh          * ((unsigned)h1 < (unsigned)HH ? 1.0f : 0.0f);
    float ww0 = (1.0f - fw) * ((unsigned)w0 < (unsigned)WW ? 1.0f : 0.0f);
    float ww1 = fw          * ((unsigned)w1 < (unsigned)WW ? 1.0f : 0.0f);

    int d0c = min(max(d0, 0), DD - 1), d1c = min(max(d1, 0), DD - 1);
    int h0c = min(max(h0, 0), HH - 1), h1c = min(max(h1, 0), HH - 1);
    int w0c = min(max(w0, 0), WW - 1), w1c = min(max(w1, 0), WW - 1);

    const float* p00 = sbase + (d0c * HH + h0c) * WW;
    const float* p01 = sbase + (d0c * HH + h1c) * WW;
    const float* p10 = sbase + (d1c * HH + h0c) * WW;
    const float* p11 = sbase + (d1c * HH + h1c) * WW;

    return wd0 * (wh0 * (ww0 * p00[w0c] + ww1 * p00[w1c]) +
                  wh1 * (ww0 * p01[w0c] + ww1 * p01[w1c])) +
           wd1 * (wh0 * (ww0 * p10[w0c] + ww1 * p10[w1c]) +
                  wh1 * (ww0 * p11[w0c] + ww1 * p11[w1c]));
}

__global__ __launch_bounds__(1024, 8) void warp3d_kernel(
    const float* __restrict__ src, const float* __restrict__ flow,
    float* __restrict__ out) {
    __shared__ float tile[TILE_N];

    // XCD-aware swizzle: contiguous brick ranges per XCD.
    int bid = blockIdx.x;
    int wg  = (bid & 7) * CHUNK + (bid >> 3);

    int b  = wg / BRICKS_PER_B;
    int r  = wg - b * BRICKS_PER_B;
    int dt = r / (HT * WT);
    int r2 = r - dt * (HT * WT);
    int ht = r2 / WT;
    int wtile = r2 - ht * WT;

    int dB = dt * 16, hB = ht * 16, wB = wtile * 16;
    int dB4 = dB - 4, hB4 = hB - 4, wB4 = wB - 4;

    // Region strictly inside the volume -> no validity masks needed.
    bool interior = (dt >= 1) & (dt <= DT - 2) & (ht >= 1) & (ht <= HT - 2)
                  & (wtile >= 1) & (wtile <= WT - 2);

    const float* sbase = src + (size_t)b * DHW;

    // Output voxel mapping: 16 waves = 4d x 4h groups; wave = 4d x 4h x 16w.
    int tid  = threadIdx.x;
    int wave = tid >> 6;
    int lane = tid & 63;
    int d = dB + (wave >> 2) * 4 + (lane >> 4);
    int h = hB + (wave & 3) * 4 + ((lane >> 2) & 3);
    int w = wB + (lane & 3) * 4;

    size_t sOff = (size_t)(d * HH + h) * WW + w;
    const float* fb = flow + (size_t)b * 3 * DHW + sOff;
    // Issue flow loads first; they drain while staging proceeds.
    vfloat4 fld = *reinterpret_cast<const vfloat4*>(fb);
    vfloat4 flh = *reinterpret_cast<const vfloat4*>(fb + DHW);
    vfloat4 flw = *reinterpret_cast<const vfloat4*>(fb + 2 * DHW);

    // ---- Stage src region into LDS (coalesced float4 reads) ----
    // 576 rows (24d x 24h) x 24 floats = 3456 float4 chunks, grid-stride.
    bool wedge = (wtile == 0) | (wtile == WT - 1);  // w-halo crosses volume
    for (int u = tid; u < SCHUNKS; u += BLOCK) {
        int row = u / 6;                   // 0..575
        int c   = u - row * 6;             // 0..5
        int ld = row / RH, lh = row - ld * RH;
        int dg = min(max(dB4 + ld, 0), DD - 1);
        int hg = min(max(hB4 + lh, 0), HH - 1);
        const float* grow = sbase + (size_t)(dg * HH + hg) * WW;
        int wg0 = wB4 + 4 * c;             // 16B-aligned for interior tiles
        vfloat4 v;
        if (!wedge) {
            v = *reinterpret_cast<const vfloat4*>(grow + wg0);
        } else {
            v.x = grow[min(max(wg0 + 0, 0), WW - 1)];
            v.y = grow[min(max(wg0 + 1, 0), WW - 1)];
            v.z = grow[min(max(wg0 + 2, 0), WW - 1)];
            v.w = grow[min(max(wg0 + 3, 0), WW - 1)];
        }
        float* dst = &tile[row * RWP + 4 * c];   // stride 25: scalar writes
        dst[0] = v.x; dst[1] = v.y; dst[2] = v.z; dst[3] = v.w;
    }
    __syncthreads();

    float df = (float)d, hf = (float)h, wf = (float)w;
    float fdv[4] = {fld.x, fld.y, fld.z, fld.w};
    float fhv[4] = {flh.x, flh.y, flh.z, flh.w};
    float fwv[4] = {flw.x, flw.y, flw.z, flw.w};

    float cdv[4], chv[4], cwv[4];
    float fdq[4], fhq[4], fwq[4];
    int   base[4];
    bool  okv[4];
    #pragma unroll
    for (int k = 0; k < 4; ++k) {
        float cd = df + fdv[k], ch = hf + fhv[k], cw = wf + (float)k + fwv[k];
        cdv[k] = cd; chv[k] = ch; cwv[k] = cw;
        float d0f = floorf(cd), h0f = floorf(ch), w0f = floorf(cw);
        fdq[k] = cd - d0f; fhq[k] = ch - h0f; fwq[k] = cw - w0f;
        int rd = (int)d0f - dB4, rh = (int)h0f - hB4, rw = (int)w0f - wB4;
        okv[k] = ((unsigned)rd < (unsigned)(RD - 1)) &
                 ((unsigned)rh < (unsigned)(RH - 1)) &
                 ((unsigned)rw < (unsigned)(RWE - 1));
        base[k] = (rd * RH + rh) * RWP + rw;
    }
    bool allin = okv[0] & okv[1] & okv[2] & okv[3];

    float res[4];
    if (allin) {
        if (interior) {
            // Mask-free: 8 LDS taps + 7-lerp tree per voxel.
            #pragma unroll
            for (int k = 0; k < 4; ++k) {
                int b0 = base[k];
                float fw = fwq[k], fh = fhq[k], fd = fdq[k];
                float v0 = tile[b0],                 v1 = tile[b0 + 1];
                float v2 = tile[b0 + RWP],           v3 = tile[b0 + RWP + 1];
                float v4 = tile[b0 + RH * RWP],      v5 = tile[b0 + RH * RWP + 1];
                float v6 = tile[b0 + RH * RWP + RWP];
                float v7 = tile[b0 + RH * RWP + RWP + 1];
                float x0 = fmaf(fw, v1 - v0, v0);
                float x1 = fmaf(fw, v3 - v2, v2);
                float x2 = fmaf(fw, v5 - v4, v4);
                float x3 = fmaf(fw, v7 - v6, v6);
                float y0 = fmaf(fh, x1 - x0, x0);
                float y1 = fmaf(fh, x3 - x2, x2);
                res[k] = fmaf(fd, y1 - y0, y0);
            }
        } else {
            // Edge block: validity folded into weights (zeros padding).
            #pragma unroll
            for (int k = 0; k < 4; ++k) {
                float cd = cdv[k], ch = chv[k], cw = cwv[k];
                int d0 = (int)floorf(cd), h0 = (int)floorf(ch),
                    w0 = (int)floorf(cw);
                float fd = fdq[k], fh = fhq[k], fw = fwq[k];
                float wd0 = (1.0f - fd) * ((unsigned)d0 < (unsigned)DD ? 1.0f : 0.0f);
                float wd1 = fd    * ((unsigned)(d0 + 1) < (unsigned)DD ? 1.0f : 0.0f);
                float wh0 = (1.0f - fh) * ((unsigned)h0 < (unsigned)HH ? 1.0f : 0.0f);
                float wh1 = fh    * ((unsigned)(h0 + 1) < (unsigned)HH ? 1.0f : 0.0f);
                float ww0 = (1.0f - fw) * ((unsigned)w0 < (unsigned)WW ? 1.0f : 0.0f);
                float ww1 = fw    * ((unsigned)(w0 + 1) < (unsigned)WW ? 1.0f : 0.0f);
                int b0 = base[k];
                float v0 = tile[b0],                 v1 = tile[b0 + 1];
                float v2 = tile[b0 + RWP],           v3 = tile[b0 + RWP + 1];
                float v4 = tile[b0 + RH * RWP],      v5 = tile[b0 + RH * RWP + 1];
                float v6 = tile[b0 + RH * RWP + RWP];
                float v7 = tile[b0 + RH * RWP + RWP + 1];
                float a = wd0 * wh0, bq = wd0 * wh1, cq = wd1 * wh0, dq = wd1 * wh1;
                res[k] = a  * (ww0 * v0 + ww1 * v1) + bq * (ww0 * v2 + ww1 * v3) +
                         cq * (ww0 * v4 + ww1 * v5) + dq * (ww0 * v6 + ww1 * v7);
            }
        }
    } else {
        // Rare (flow beyond halo): recompute fully from global.
        #pragma unroll
        for (int k = 0; k < 4; ++k)
            res[k] = trilerp_global(sbase, cdv[k], chv[k], cwv[k]);
    }

    vfloat4 o4 = {res[0], res[1], res[2], res[3]};
    *reinterpret_cast<vfloat4*>(out + (size_t)b * DHW + sOff) = o4;
}

extern "C" void kernel_launch(void* const* d_in, const int* in_sizes, int n_in,
                              void* d_out, int out_size, void* d_ws, size_t ws_size,
                              hipStream_t stream) {
    const float* src  = (const float*)d_in[0];
    const float* flow = (const float*)d_in[1];
    float* out = (float*)d_out;

    warp3d_kernel<<<NWG, BLOCK, 0, stream>>>(src, flow, out);
}